// Round 11
// baseline (161.195 us; speedup 1.0000x reference)
//
#include <hip/hip_runtime.h>
#include <stdint.h>

#define IN_F 4096
#define OUT_F 4096
#define M_ROWS 4096
#define BM 256
#define BN 256
#define BK 64
#define BLK_B 16384              // one k-half block (256 rows x 32k x 2B)
#define TILE_B (4 * BLK_B)       // Ak0,Bk0,Ak1,Bk1 = 64 KiB

typedef __attribute__((ext_vector_type(8))) short bf16x8;
typedef __attribute__((ext_vector_type(4))) float f32x4;
typedef __attribute__((ext_vector_type(4))) float f4;
typedef __attribute__((ext_vector_type(8))) unsigned short u16x8;

__device__ __forceinline__ unsigned short f32_to_bf16_rne(float f) {
    uint32_t u = __float_as_uint(f);
    u += 0x7FFFu + ((u >> 16) & 1u);
    return (unsigned short)(u >> 16);
}

// ---- prepass: x->bf16 [0,8192); W expand [8192,16384); C bias-init cols<2048 [16384,20480) ----
__global__ __launch_bounds__(256) void prep_kernel(const float* __restrict__ x,
                                                   const float* __restrict__ wsrc,
                                                   const float* __restrict__ bias,
                                                   unsigned short* __restrict__ xb,
                                                   unsigned short* __restrict__ wb,
                                                   float* __restrict__ C) {
    int b = blockIdx.x;
    if (b < 8192) {
        size_t g = (size_t)b * 256 + threadIdx.x;
        const f4* xp = (const f4*)x + g * 2;
        f4 a = xp[0], c = xp[1];
        u16x8 r;
        r[0] = f32_to_bf16_rne(a[0]); r[1] = f32_to_bf16_rne(a[1]);
        r[2] = f32_to_bf16_rne(a[2]); r[3] = f32_to_bf16_rne(a[3]);
        r[4] = f32_to_bf16_rne(c[0]); r[5] = f32_to_bf16_rne(c[1]);
        r[6] = f32_to_bf16_rne(c[2]); r[7] = f32_to_bf16_rne(c[3]);
        *((u16x8*)xb + g) = r;
    } else if (b < 16384) {
        size_t g = (size_t)(b - 8192) * 256 + threadIdx.x;
        int o  = (int)(g >> 9);
        int i0 = ((int)g & 511) << 3;
        int bs = (o >> 8) << 8;            // GEMM reads k >= 256-aligned block start
        if (i0 >= bs) {
            int off = o * IN_F - ((o * (o - 1)) >> 1);
            u16x8 r;
#pragma unroll
            for (int j = 0; j < 8; ++j) {
                int i = i0 + j;
                float v = (i >= o) ? wsrc[off + (i - o)] : 0.0f;
                r[j] = f32_to_bf16_rne(v);
            }
            *((u16x8*)wb + g) = r;
        }
    } else {
        // bias-init C[:, 0:2048] (split-K atomic region)
        size_t g = (size_t)(b - 16384) * 256 + threadIdx.x;   // 1M threads x 8 floats
        int row = (int)(g >> 8);
        int c0  = ((int)g & 255) << 3;
        f4 b4a = *(const f4*)(bias + c0);
        f4 b4b = *(const f4*)(bias + c0 + 4);
        *(f4*)(C + (size_t)row * OUT_F + c0)     = b4a;
        *(f4*)(C + (size_t)row * OUT_F + c0 + 4) = b4b;
    }
}

// ---- stage one k-half block (256 rows x 32 k) via 2 global_load_lds per wave ----
// LDS block layout: byte(row, slot) = row*64 + (slot ^ ((row>>1)&3))*16, slot = 16B k-granule
// dest is linear (base + lane*16); source slot pre-swizzled so read-side XOR matches.
__device__ __forceinline__ void stage_kh(const unsigned short* __restrict__ G,
                                         char* blk, int gr0, int k0, int kh,
                                         int wid, int lane) {
    const int r  = lane >> 2;                    // 0..15 row within unit
    const int sd = lane & 3;                     // dest slot
    const int ss = sd ^ ((r >> 1) & 3);          // pre-swizzled source slot
    const size_t coff = (size_t)(k0 + kh * 32 + ss * 8);
#pragma unroll
    for (int q = 0; q < 2; ++q) {
        const int u = wid * 2 + q;               // 16-row unit 0..15
        const unsigned short* src = G + (size_t)(gr0 + u * 16 + r) * IN_F + coff;
        __builtin_amdgcn_global_load_lds(
            (const __attribute__((address_space(1))) void*)src,
            (__attribute__((address_space(3))) void*)(blk + u * 1024), 16, 0, 0);
    }
}

__device__ __forceinline__ const bf16x8* frag(const char* blk, int row, int khalf) {
    return (const bf16x8*)(blk + row * 64 + ((khalf ^ ((row >> 1) & 3)) * 16));
}

// ---- main GEMM: 256x256 tiles, 8 waves (2M x 4N), wave 128x64, 4-phase K-loop ----
// Jobs: tn 0-7 split-K-2 (atomicAdd, bias pre-init); tn 8-15 whole (direct store+bias).
__global__ __launch_bounds__(512) void tri_gemm_kernel(const unsigned short* __restrict__ A,
                                                       const unsigned short* __restrict__ W,
                                                       const float* __restrict__ bias,
                                                       float* __restrict__ C) {
    __shared__ __align__(16) char smem[2 * TILE_B];   // 128 KiB double buffer

    // ---- job decode (LPT order: sizes desc across blockIdx) ----
    const int b = blockIdx.x;
    int tn, tm, seg, isSeg;
    if (b < 48)       { int i = b;       if (i < 32) { isSeg = 1; tn = 0; tm = i >> 1; seg = i & 1; } else { isSeg = 0; tn = 8;  tm = i - 32; seg = 0; } }
    else if (b < 80)  { int i = b - 48;  isSeg = 1; tn = 1; tm = i >> 1; seg = i & 1; }
    else if (b < 128) { int i = b - 80;  if (i < 32) { isSeg = 1; tn = 2; tm = i >> 1; seg = i & 1; } else { isSeg = 0; tn = 9;  tm = i - 32; seg = 0; } }
    else if (b < 160) { int i = b - 128; isSeg = 1; tn = 3; tm = i >> 1; seg = i & 1; }
    else if (b < 208) { int i = b - 160; if (i < 32) { isSeg = 1; tn = 4; tm = i >> 1; seg = i & 1; } else { isSeg = 0; tn = 10; tm = i - 32; seg = 0; } }
    else if (b < 240) { int i = b - 208; isSeg = 1; tn = 5; tm = i >> 1; seg = i & 1; }
    else if (b < 288) { int i = b - 240; if (i < 32) { isSeg = 1; tn = 6; tm = i >> 1; seg = i & 1; } else { isSeg = 0; tn = 11; tm = i - 32; seg = 0; } }
    else if (b < 320) { int i = b - 288; isSeg = 1; tn = 7; tm = i >> 1; seg = i & 1; }
    else              { int i = b - 320; isSeg = 0; tn = 12 + (i >> 4); tm = i & 15; seg = 0; }

    const int m_base = tm * BM;
    const int n_base = tn * BN;
    int kb, nt;
    if (isSeg) { const int half = 2048 - 128 * tn; kb = tn * 256 + seg * half; nt = half / 64; }
    else       { kb = tn * 256; nt = (IN_F - tn * 256) / 64; }

    const int tid  = threadIdx.x;
    const int wid  = tid >> 6;
    const int lane = tid & 63;
    const int wr = wid >> 2;            // 0..1 (128-row band)
    const int wc = wid & 3;             // 0..3 (64-col band)
    const int frow  = lane & 15;
    const int khalf = lane >> 4;

    f32x4 acc[8][4];
#pragma unroll
    for (int i = 0; i < 8; ++i)
#pragma unroll
        for (int j = 0; j < 4; ++j) acc[i][j] = (f32x4){0.f, 0.f, 0.f, 0.f};

    // prologue: stage all 4 blocks of tile 0 in ledger order (8 loads/wave outstanding)
    {
        char* buf0 = smem;
        stage_kh(A, buf0,             m_base, kb, 0, wid, lane);
        stage_kh(W, buf0 + BLK_B,     n_base, kb, 0, wid, lane);
        stage_kh(A, buf0 + 2 * BLK_B, m_base, kb, 1, wid, lane);
        stage_kh(W, buf0 + 3 * BLK_B, n_base, kb, 1, wid, lane);
    }

    for (int t = 0; t < nt; ++t) {
        char* cur = smem + (size_t)(t & 1) * TILE_B;
        char* nxt = smem + (size_t)((t + 1) & 1) * TILE_B;
        const int knext = kb + (t + 1) * BK;
        const bool more = (t + 1 < nt);
        const int arow = wr * 128 + frow;
        const int brow = wc * 64 + frow;

        bf16x8 af[4], ag[4], bfr[4];

        // ======== phase 1: publish Ak0/Bk0, compute mi0-3 x kh0 ========
        asm volatile("s_waitcnt vmcnt(4)" ::: "memory");   // retire Ak0,Bk0 of tile t
        __builtin_amdgcn_sched_barrier(0);
        __builtin_amdgcn_s_barrier();
        __builtin_amdgcn_sched_barrier(0);
#pragma unroll
        for (int mi = 0; mi < 4; ++mi) af[mi]  = *frag(cur,             arow + mi * 16, khalf);
#pragma unroll
        for (int nj = 0; nj < 4; ++nj) bfr[nj] = *frag(cur + BLK_B,     brow + nj * 16, khalf);
        if (more) stage_kh(A, nxt, m_base, knext, 0, wid, lane);
        asm volatile("s_waitcnt lgkmcnt(0)" ::: "memory");
        __builtin_amdgcn_sched_barrier(0);
        __builtin_amdgcn_s_setprio(1);
#pragma unroll
        for (int mi = 0; mi < 4; ++mi)
#pragma unroll
            for (int nj = 0; nj < 4; ++nj)
                acc[mi][nj] = __builtin_amdgcn_mfma_f32_16x16x32_bf16(af[mi], bfr[nj], acc[mi][nj], 0, 0, 0);
        __builtin_amdgcn_s_setprio(0);

        // ======== phase 2: compute mi4-7 x kh0 (B reused) ========
#pragma unroll
        for (int mi = 0; mi < 4; ++mi) ag[mi] = *frag(cur, arow + 64 + mi * 16, khalf);
        if (more) stage_kh(W, nxt + BLK_B, n_base, knext, 0, wid, lane);
        asm volatile("s_waitcnt lgkmcnt(0)" ::: "memory");
        __builtin_amdgcn_sched_barrier(0);
        __builtin_amdgcn_s_setprio(1);
#pragma unroll
        for (int mi = 0; mi < 4; ++mi)
#pragma unroll
            for (int nj = 0; nj < 4; ++nj)
                acc[4 + mi][nj] = __builtin_amdgcn_mfma_f32_16x16x32_bf16(ag[mi], bfr[nj], acc[4 + mi][nj], 0, 0, 0);
        __builtin_amdgcn_s_setprio(0);

        // ======== phase 3: publish Ak1/Bk1, compute mi0-3 x kh1 ========
        if (more) { asm volatile("s_waitcnt vmcnt(4)" ::: "memory"); }
        else      { asm volatile("s_waitcnt vmcnt(0)" ::: "memory"); }
        __builtin_amdgcn_sched_barrier(0);
        __builtin_amdgcn_s_barrier();
        __builtin_amdgcn_sched_barrier(0);
#pragma unroll
        for (int mi = 0; mi < 4; ++mi) af[mi]  = *frag(cur + 2 * BLK_B, arow + mi * 16, khalf);
#pragma unroll
        for (int nj = 0; nj < 4; ++nj) bfr[nj] = *frag(cur + 3 * BLK_B, brow + nj * 16, khalf);
        if (more) stage_kh(A, nxt + 2 * BLK_B, m_base, knext, 1, wid, lane);
        asm volatile("s_waitcnt lgkmcnt(0)" ::: "memory");
        __builtin_amdgcn_sched_barrier(0);
        __builtin_amdgcn_s_setprio(1);
#pragma unroll
        for (int mi = 0; mi < 4; ++mi)
#pragma unroll
            for (int nj = 0; nj < 4; ++nj)
                acc[mi][nj] = __builtin_amdgcn_mfma_f32_16x16x32_bf16(af[mi], bfr[nj], acc[mi][nj], 0, 0, 0);
        __builtin_amdgcn_s_setprio(0);

        // ======== phase 4: compute mi4-7 x kh1 ========
#pragma unroll
        for (int mi = 0; mi < 4; ++mi) ag[mi] = *frag(cur + 2 * BLK_B, arow + 64 + mi * 16, khalf);
        if (more) stage_kh(W, nxt + 3 * BLK_B, n_base, knext, 1, wid, lane);
        asm volatile("s_waitcnt lgkmcnt(0)" ::: "memory");
        __builtin_amdgcn_sched_barrier(0);
        __builtin_amdgcn_s_setprio(1);
#pragma unroll
        for (int mi = 0; mi < 4; ++mi)
#pragma unroll
            for (int nj = 0; nj < 4; ++nj)
                acc[4 + mi][nj] = __builtin_amdgcn_mfma_f32_16x16x32_bf16(ag[mi], bfr[nj], acc[4 + mi][nj], 0, 0, 0);
        __builtin_amdgcn_s_setprio(0);
    }

    // ---- epilogue: D layout col=lane&15, row=(lane>>4)*4+q ----
    const int col0 = n_base + wc * 64;
    const int row0 = m_base + wr * 128;
    if (isSeg) {
#pragma unroll
        for (int nj = 0; nj < 4; ++nj) {
            const int col = col0 + nj * 16 + frow;
#pragma unroll
            for (int mi = 0; mi < 8; ++mi) {
                const int r0 = row0 + mi * 16 + khalf * 4;
#pragma unroll
                for (int q = 0; q < 4; ++q)
                    atomicAdd(&C[(size_t)(r0 + q) * OUT_F + col], acc[mi][nj][q]);
            }
        }
    } else {
#pragma unroll
        for (int nj = 0; nj < 4; ++nj) {
            const int col = col0 + nj * 16 + frow;
            const float bv = bias[col];
#pragma unroll
            for (int mi = 0; mi < 8; ++mi) {
                const int r0 = row0 + mi * 16 + khalf * 4;
#pragma unroll
                for (int q = 0; q < 4; ++q)
                    C[(size_t)(r0 + q) * OUT_F + col] = acc[mi][nj][q] + bv;
            }
        }
    }
}

extern "C" void kernel_launch(void* const* d_in, const int* in_sizes, int n_in,
                              void* d_out, int out_size, void* d_ws, size_t ws_size,
                              hipStream_t stream) {
    const float* x    = (const float*)d_in[0];
    const float* w    = (const float*)d_in[1];
    const float* bias = (const float*)d_in[2];
    float* out = (float*)d_out;

    unsigned short* xb = (unsigned short*)d_ws;                  // 32 MiB bf16 x
    unsigned short* wb = xb + (size_t)M_ROWS * IN_F;             // 32 MiB bf16 dense W

    prep_kernel<<<20480, 256, 0, stream>>>(x, w, bias, xb, wb, out);
    tri_gemm_kernel<<<384, 512, 0, stream>>>(xb, wb, bias, out);
}

// Round 14
// 117.966 us; speedup vs baseline: 1.3665x; 1.3665x over previous
//
#include <hip/hip_runtime.h>
#include <stdint.h>

#define IN_F 4096
#define OUT_F 4096
#define M_ROWS 4096   // B*S
#define BM 256
#define BN 128
#define BK 64
#define LDA_B (BM * BK * 2)        // 32 KiB
#define LDB_B (BN * BK * 2)        // 16 KiB

typedef __attribute__((ext_vector_type(8))) short bf16x8;
typedef __attribute__((ext_vector_type(4))) float f32x4;
typedef __attribute__((ext_vector_type(4))) float f4;
typedef __attribute__((ext_vector_type(8))) unsigned short u16x8;

__device__ __forceinline__ unsigned short f32_to_bf16_rne(float f) {
    uint32_t u = __float_as_uint(f);
    u += 0x7FFFu + ((u >> 16) & 1u);
    return (unsigned short)(u >> 16);
}

// ---- merged prepass: x fp32->bf16 (blocks [0,8192)), W expand (blocks [8192,16384)) ----
__global__ __launch_bounds__(256) void prep_kernel(const float* __restrict__ x,
                                                   const float* __restrict__ wsrc,
                                                   unsigned short* __restrict__ xb,
                                                   unsigned short* __restrict__ wb) {
    int b = blockIdx.x;
    if (b < 8192) {
        size_t g = (size_t)b * 256 + threadIdx.x;   // one per 8 elems
        const f4* xp = (const f4*)x + g * 2;
        f4 a = xp[0], c = xp[1];
        u16x8 r;
        r[0] = f32_to_bf16_rne(a[0]); r[1] = f32_to_bf16_rne(a[1]);
        r[2] = f32_to_bf16_rne(a[2]); r[3] = f32_to_bf16_rne(a[3]);
        r[4] = f32_to_bf16_rne(c[0]); r[5] = f32_to_bf16_rne(c[1]);
        r[6] = f32_to_bf16_rne(c[2]); r[7] = f32_to_bf16_rne(c[3]);
        *((u16x8*)xb + g) = r;
    } else {
        size_t g = (size_t)(b - 8192) * 256 + threadIdx.x;
        int o  = (int)(g >> 9);
        int i0 = ((int)g & 511) << 3;
        int bs = (o >> 7) << 7;            // GEMM never reads i < 128-aligned block start
        if (i0 >= bs) {
            int off = o * IN_F - ((o * (o - 1)) >> 1);
            u16x8 r;
#pragma unroll
            for (int j = 0; j < 8; ++j) {
                int i = i0 + j;
                float v = (i >= o) ? wsrc[off + (i - o)] : 0.0f;
                r[j] = f32_to_bf16_rne(v);
            }
            *((u16x8*)wb + g) = r;
        }
    }
}

// ---- A staging: 8-row x 128B unit via global_load_lds; dest linear, source pre-swizzled ----
// LDS row layout: [row][8 slots x 16B], byte(row,slot) = row*128 + (slot ^ (row&7))*16
__device__ __forceinline__ void stage16(const unsigned short* __restrict__ G,
                                        char* lds_dst, int gr0, int k0, int lane) {
    const int lrow  = lane >> 3;                 // 0..7
    const int gslot = (lane & 7) ^ lrow;         // pre-swizzled source slot
    const unsigned short* src = G + (size_t)(gr0 + lrow) * IN_F + k0 + gslot * 8;
    __builtin_amdgcn_global_load_lds(
        (const __attribute__((address_space(1))) void*)src,
        (__attribute__((address_space(3))) void*)lds_dst, 16, 0, 0);
}

__device__ __forceinline__ void stageA(const unsigned short* __restrict__ A,
                                       char* bufA, int m_base, int k0,
                                       int wid, int lane) {
#pragma unroll
    for (int q = 0; q < 4; ++q) {                // A: 32 rows per wave (4 DMA ops/thread)
        const int r0 = q * 64 + wid * 8;
        stage16(A, bufA + r0 * 128, m_base + r0, k0, lane);
    }
}

// ---- B reg-staging: identical per-lane source addressing, result held in VGPRs ----
__device__ __forceinline__ void loadB(const unsigned short* __restrict__ W,
                                      bf16x8 (&reg)[2], int n_base, int k0,
                                      int wid, int lane) {
    const int lrow  = lane >> 3;
    const int gslot = (lane & 7) ^ lrow;
#pragma unroll
    for (int q = 0; q < 2; ++q) {
        const int row = q * 64 + wid * 8 + lrow;
        reg[q] = *(const bf16x8*)(W + (size_t)(n_base + row) * IN_F + k0 + gslot * 8);
    }
}

// ds_write to the SAME linear dest global_load_lds would use -> identical LDS layout
__device__ __forceinline__ void writeB(char* bufB, bf16x8 (&reg)[2], int wid, int lane) {
#pragma unroll
    for (int q = 0; q < 2; ++q) {
        const int r0 = q * 64 + wid * 8;
        *(bf16x8*)(bufB + r0 * 128 + lane * 16) = reg[q];   // stride-1 lanes: conflict-free
    }
}

__device__ __forceinline__ const bf16x8* lds_frag(const char* buf, int row, int slot) {
    return (const bf16x8*)(buf + row * 128 + ((slot ^ (row & 7)) * 16));
}

// ---- main GEMM: C[m][n] = sum_{k>=n_base} A[m][k]*W[n][k] + bias[n] ----
// R2-exact schedule (depth-3, entry vmcnt(6), ONE barrier/tile, single read+MFMA burst);
// only change vs R2: B staged via global_load->reg->ds_write (off the DMA engine).
__global__ __launch_bounds__(512, 2) void tri_gemm_kernel(const unsigned short* __restrict__ A,
                                                          const unsigned short* __restrict__ W,
                                                          const float* __restrict__ bias,
                                                          float* __restrict__ C) {
    __shared__ __align__(16) char smem[3 * LDA_B + 3 * LDB_B];   // 144 KiB

    const int u = blockIdx.x;
    const int tile_n = u >> 4;          // desc-K order -> greedy LPT, 66 K-tiles/CU uniform
    const int tile_m = u & 15;
    const int m_base = tile_m * BM;
    const int n_base = tile_n * BN;
    const int nt = (IN_F - n_base) / BK;   // 64 - 2*tile_n, even, min 2

    const int tid  = threadIdx.x;
    const int wid  = tid >> 6;
    const int lane = tid & 63;
    const int wr = wid >> 1;            // 0..3  (64-row band)
    const int wc = wid & 1;             // 0..1  (64-col band)
    const int frow  = lane & 15;
    const int khalf = lane >> 4;

    char* a0 = smem;               char* a1 = smem + LDA_B;   char* a2 = smem + 2 * LDA_B;
    char* b0 = smem + 3 * LDA_B;   char* b1 = b0 + LDB_B;     char* b2 = b0 + 2 * LDB_B;

    f32x4 acc[4][4];
#pragma unroll
    for (int i = 0; i < 4; ++i)
#pragma unroll
        for (int j = 0; j < 4; ++j) acc[i][j] = (f32x4){0.f, 0.f, 0.f, 0.f};

    bf16x8 regE[2], regO[2];    // B-reg buffers, static parity via x2 unroll

    // prologue: stage sets for tiles 0,1 -> 12 vmem ops outstanding per thread
    stageA(A, a0, m_base, n_base, wid, lane);
    loadB(W, regE, n_base, n_base, wid, lane);
    stageA(A, a1, m_base, n_base + BK, wid, lane);
    loadB(W, regO, n_base, n_base + BK, wid, lane);

    // iter t: entry vmcnt(6) drains {A(t) DMA, B(t) regs}; write B(t); barrier publishes;
    // then stage set(t+2); compute R2-exact burst.
    auto iter = [&](int t, bf16x8 (&reg)[2]) {
        if (t + 1 < nt) { asm volatile("s_waitcnt vmcnt(6)" ::: "memory"); }
        else            { asm volatile("s_waitcnt vmcnt(0)" ::: "memory"); }
        __builtin_amdgcn_sched_barrier(0);
        writeB(b0, reg, wid, lane);                          // B(t) -> current buffer
        asm volatile("s_waitcnt lgkmcnt(0)" ::: "memory");   // writes visible before barrier
        __builtin_amdgcn_sched_barrier(0);
        __builtin_amdgcn_s_barrier();                        // publish A(t)+B(t)
        __builtin_amdgcn_sched_barrier(0);

        if (t + 2 < nt) {
            stageA(A, a2, m_base, n_base + (t + 2) * BK, wid, lane);
            loadB(W, reg, n_base, n_base + (t + 2) * BK, wid, lane);  // reuse freed regs
        }

        const char* bufA = a0;
        const char* bufB = b0;
#pragma unroll
        for (int ks = 0; ks < 2; ++ks) {
            bf16x8 af[4], bfr[4];
#pragma unroll
            for (int i = 0; i < 4; ++i)
                af[i] = *lds_frag(bufA, wr * 64 + i * 16 + frow, ks * 4 + khalf);
#pragma unroll
            for (int j = 0; j < 4; ++j)
                bfr[j] = *lds_frag(bufB, wc * 64 + j * 16 + frow, ks * 4 + khalf);
            __builtin_amdgcn_s_setprio(1);
#pragma unroll
            for (int i = 0; i < 4; ++i)
#pragma unroll
                for (int j = 0; j < 4; ++j)
                    acc[i][j] = __builtin_amdgcn_mfma_f32_16x16x32_bf16(af[i], bfr[j], acc[i][j], 0, 0, 0);
            __builtin_amdgcn_s_setprio(0);
        }

        asm volatile("s_waitcnt lgkmcnt(0)" ::: "memory");   // reads retired before rotation
        __builtin_amdgcn_sched_barrier(0);

        char* ta = a0; a0 = a1; a1 = a2; a2 = ta;            // rotate roles
        char* tb = b0; b0 = b1; b1 = b2; b2 = tb;
    };

    for (int t = 0; t < nt; t += 2) {   // nt always even
        iter(t, regE);
        iter(t + 1, regO);
    }

    // ---- epilogue: D layout col=lane&15, row=(lane>>4)*4+q ----
    const int col0 = n_base + wc * 64;
    const int row0 = m_base + wr * 64;
#pragma unroll
    for (int nj = 0; nj < 4; ++nj) {
        const int col = col0 + nj * 16 + frow;
        const float bv = bias[col];
#pragma unroll
        for (int mi = 0; mi < 4; ++mi) {
            const int rbase = row0 + mi * 16 + khalf * 4;
#pragma unroll
            for (int q = 0; q < 4; ++q) {
                C[(size_t)(rbase + q) * OUT_F + col] = acc[mi][nj][q] + bv;
            }
        }
    }
}

extern "C" void kernel_launch(void* const* d_in, const int* in_sizes, int n_in,
                              void* d_out, int out_size, void* d_ws, size_t ws_size,
                              hipStream_t stream) {
    const float* x    = (const float*)d_in[0];
    const float* w    = (const float*)d_in[1];
    const float* bias = (const float*)d_in[2];
    float* out = (float*)d_out;

    unsigned short* xb = (unsigned short*)d_ws;                  // 32 MiB bf16 x
    unsigned short* wb = xb + (size_t)M_ROWS * IN_F;             // 32 MiB bf16 dense W

    prep_kernel<<<16384, 256, 0, stream>>>(x, w, xb, wb);
    tri_gemm_kernel<<<512, 512, 0, stream>>>(xb, wb, bias, out);
}

// Round 15
// 106.825 us; speedup vs baseline: 1.5090x; 1.1043x over previous
//
#include <hip/hip_runtime.h>
#include <stdint.h>

#define IN_F 4096
#define OUT_F 4096
#define M_ROWS 4096   // B*S
#define BM 128
#define BN 128
#define BK 64
#define ABUF_B (BM * BK * 2)       // 16 KiB
#define BBUF_B (BN * BK * 2)       // 16 KiB
#define BUF_B (ABUF_B + BBUF_B)    // 32 KiB per depth

typedef __attribute__((ext_vector_type(8))) short bf16x8;
typedef __attribute__((ext_vector_type(4))) float f32x4;
typedef __attribute__((ext_vector_type(4))) float f4;
typedef __attribute__((ext_vector_type(8))) unsigned short u16x8;

__device__ __forceinline__ unsigned short f32_to_bf16_rne(float f) {
    uint32_t u = __float_as_uint(f);
    u += 0x7FFFu + ((u >> 16) & 1u);
    return (unsigned short)(u >> 16);
}

// ---- merged prepass: x fp32->bf16 (blocks [0,8192)), W expand (blocks [8192,16384)) ----
__global__ __launch_bounds__(256) void prep_kernel(const float* __restrict__ x,
                                                   const float* __restrict__ wsrc,
                                                   unsigned short* __restrict__ xb,
                                                   unsigned short* __restrict__ wb) {
    int b = blockIdx.x;
    if (b < 8192) {
        size_t g = (size_t)b * 256 + threadIdx.x;   // one per 8 elems
        const f4* xp = (const f4*)x + g * 2;
        f4 a = xp[0], c = xp[1];
        u16x8 r;
        r[0] = f32_to_bf16_rne(a[0]); r[1] = f32_to_bf16_rne(a[1]);
        r[2] = f32_to_bf16_rne(a[2]); r[3] = f32_to_bf16_rne(a[3]);
        r[4] = f32_to_bf16_rne(c[0]); r[5] = f32_to_bf16_rne(c[1]);
        r[6] = f32_to_bf16_rne(c[2]); r[7] = f32_to_bf16_rne(c[3]);
        *((u16x8*)xb + g) = r;
    } else {
        size_t g = (size_t)(b - 8192) * 256 + threadIdx.x;
        int o  = (int)(g >> 9);
        int i0 = ((int)g & 511) << 3;
        int bs = (o >> 7) << 7;            // GEMM never reads i < 128-aligned block start
        if (i0 >= bs) {
            int off = o * IN_F - ((o * (o - 1)) >> 1);
            u16x8 r;
#pragma unroll
            for (int j = 0; j < 8; ++j) {
                int i = i0 + j;
                float v = (i >= o) ? wsrc[off + (i - o)] : 0.0f;
                r[j] = f32_to_bf16_rne(v);
            }
            *((u16x8*)wb + g) = r;
        }
    }
}

// ---- staging: 8-row x 128B unit via global_load_lds; dest linear, source pre-swizzled ----
// LDS row layout: [row][8 slots x 16B], byte(row,slot) = row*128 + (slot ^ (row&7))*16
__device__ __forceinline__ void stage16(const unsigned short* __restrict__ G,
                                        char* lds_dst, int gr0, int k0, int lane) {
    const int lrow  = lane >> 3;                 // 0..7
    const int gslot = (lane & 7) ^ lrow;         // pre-swizzled source slot
    const unsigned short* src = G + (size_t)(gr0 + lrow) * IN_F + k0 + gslot * 8;
    __builtin_amdgcn_global_load_lds(
        (const __attribute__((address_space(1))) void*)src,
        (__attribute__((address_space(3))) void*)lds_dst, 16, 0, 0);
}

// one K64-tile: A 128x64 + B 128x64, 4 waves -> 8 gload_lds per thread
__device__ __forceinline__ void stage_tile(const unsigned short* __restrict__ A,
                                           const unsigned short* __restrict__ W,
                                           char* buf, int m_base, int n_base, int k0,
                                           int wid, int lane) {
    char* bufA = buf;
    char* bufB = buf + ABUF_B;
#pragma unroll
    for (int q = 0; q < 4; ++q) {                // A: 32 rows per wave
        const int r0 = q * 32 + wid * 8;
        stage16(A, bufA + r0 * 128, m_base + r0, k0, lane);
    }
#pragma unroll
    for (int q = 0; q < 4; ++q) {                // B: 32 rows per wave
        const int r0 = q * 32 + wid * 8;
        stage16(W, bufB + r0 * 128, n_base + r0, k0, lane);
    }
}

__device__ __forceinline__ const bf16x8* lds_frag(const char* buf, int row, int slot) {
    return (const bf16x8*)(buf + row * 128 + ((slot ^ (row & 7)) * 16));
}

// ---- main GEMM: C[m][n] = sum_{k>=n_base} A[m][k]*W[n][k] + bias[n] ----
// 128x128 tile, 4 waves (2x2, wave 64x64), depth-2 LDS = 64 KB -> 2 blocks/CU.
// Inter-block TLP de-serializes stage/read/MFMA (R5-verified mechanism) while keeping
// R2's per-tile economics (0.5 reads/MFMA, counted vmcnt, zero bank conflicts).
__global__ __launch_bounds__(256, 2) void tri_gemm_kernel(const unsigned short* __restrict__ A,
                                                          const unsigned short* __restrict__ W,
                                                          const float* __restrict__ bias,
                                                          float* __restrict__ C) {
    __shared__ __align__(16) char smem[2 * BUF_B];   // 64 KiB double buffer

    const int u = blockIdx.x;
    const int tile_n = u >> 5;          // desc-K dispatch -> greedy LPT via refill
    const int tile_m = u & 31;
    const int m_base = tile_m * BM;
    const int n_base = tile_n * BN;
    const int nt = (IN_F - n_base) / BK;   // 64 - 2*tile_n, even, min 2

    const int tid  = threadIdx.x;
    const int wid  = tid >> 6;
    const int lane = tid & 63;
    const int wr = wid >> 1;            // 0..1 (64-row band)
    const int wc = wid & 1;             // 0..1 (64-col band)
    const int frow  = lane & 15;
    const int khalf = lane >> 4;

    char* buf0 = smem;
    char* buf1 = smem + BUF_B;

    f32x4 acc[4][4];
#pragma unroll
    for (int i = 0; i < 4; ++i)
#pragma unroll
        for (int j = 0; j < 4; ++j) acc[i][j] = (f32x4){0.f, 0.f, 0.f, 0.f};

    // prologue: tiles 0,1 staged (8 loads each per thread -> 16 outstanding)
    stage_tile(A, W, buf0, m_base, n_base, n_base,      wid, lane);
    stage_tile(A, W, buf1, m_base, n_base, n_base + BK, wid, lane);

    for (int t = 0; t < nt; ++t) {
        // publish tile t: keep tile t+1's 8 loads in flight (never drain mid-loop)
        if (t + 1 < nt) { asm volatile("s_waitcnt vmcnt(8)" ::: "memory"); }
        else            { asm volatile("s_waitcnt vmcnt(0)" ::: "memory"); }
        __builtin_amdgcn_sched_barrier(0);
        __builtin_amdgcn_s_barrier();
        __builtin_amdgcn_sched_barrier(0);

        const char* cur  = (t & 1) ? buf1 : buf0;
        const char* bufA = cur;
        const char* bufB = cur + ABUF_B;

        bf16x8 af[2][4], bfr[2][4];
#pragma unroll
        for (int kh = 0; kh < 2; ++kh) {
            const int slot = kh * 4 + khalf;
#pragma unroll
            for (int mi = 0; mi < 4; ++mi)
                af[kh][mi] = *lds_frag(bufA, wr * 64 + mi * 16 + frow, slot);
#pragma unroll
            for (int nj = 0; nj < 4; ++nj)
                bfr[kh][nj] = *lds_frag(bufB, wc * 64 + nj * 16 + frow, slot);
        }
        __builtin_amdgcn_s_setprio(1);
#pragma unroll
        for (int kh = 0; kh < 2; ++kh)
#pragma unroll
            for (int mi = 0; mi < 4; ++mi)
#pragma unroll
                for (int nj = 0; nj < 4; ++nj)
                    acc[mi][nj] = __builtin_amdgcn_mfma_f32_16x16x32_bf16(af[kh][mi], bfr[kh][nj], acc[mi][nj], 0, 0, 0);
        __builtin_amdgcn_s_setprio(0);

        // WAR close: all waves' reads of buf[t&1] retired before restaging it
        asm volatile("s_waitcnt lgkmcnt(0)" ::: "memory");
        __builtin_amdgcn_sched_barrier(0);
        __builtin_amdgcn_s_barrier();
        __builtin_amdgcn_sched_barrier(0);

        if (t + 2 < nt)
            stage_tile(A, W, (t & 1) ? buf1 : buf0, m_base, n_base,
                       n_base + (t + 2) * BK, wid, lane);
    }

    // ---- epilogue: D layout col=lane&15, row=(lane>>4)*4+q ----
    const int col0 = n_base + wc * 64;
    const int row0 = m_base + wr * 64;
#pragma unroll
    for (int nj = 0; nj < 4; ++nj) {
        const int col = col0 + nj * 16 + frow;
        const float bv = bias[col];
#pragma unroll
        for (int mi = 0; mi < 4; ++mi) {
            const int rbase = row0 + mi * 16 + khalf * 4;
#pragma unroll
            for (int q = 0; q < 4; ++q) {
                C[(size_t)(rbase + q) * OUT_F + col] = acc[mi][nj][q] + bv;
            }
        }
    }
}

extern "C" void kernel_launch(void* const* d_in, const int* in_sizes, int n_in,
                              void* d_out, int out_size, void* d_ws, size_t ws_size,
                              hipStream_t stream) {
    const float* x    = (const float*)d_in[0];
    const float* w    = (const float*)d_in[1];
    const float* bias = (const float*)d_in[2];
    float* out = (float*)d_out;

    unsigned short* xb = (unsigned short*)d_ws;                  // 32 MiB bf16 x
    unsigned short* wb = xb + (size_t)M_ROWS * IN_F;             // 32 MiB bf16 dense W

    prep_kernel<<<16384, 256, 0, stream>>>(x, w, xb, wb);
    tri_gemm_kernel<<<1024, 256, 0, stream>>>(xb, wb, bias, out);
}